// Round 2
// baseline (664.330 us; speedup 1.0000x reference)
//
#include <hip/hip_runtime.h>

#define N_NODES 100000
#define N_EDGES 1250000
#define D 64
#define NPB 256                  // nodes per coarse bucket (dst >> 8)
#define NB  391                  // ceil(N_NODES / NPB)
#define NPAD2 (NB * NPB)         // 100096
#define PTHREADS 512
#define EPT 8                    // edges per thread in place
#define EPB (PTHREADS * EPT)     // 4096 edges per block
#define NBLK ((N_EDGES + EPB - 1) / EPB)   // 306
#define CAP  4096                // static per-bucket capacity (mean 3197, +15 sigma)
#define HP 68                    // LDS leading-dim pad (16B-aligned float4 rows)
#define AP 68                    // agg LDS row stride (floats)

// ---------------- init: gcursor[b] = b*CAP ----------------
__global__ void init_kernel(int* __restrict__ gcursor) {
    int i = blockIdx.x * 256 + threadIdx.x;
    if (i < NB) gcursor[i] = i * CAP;
}

// ---------------- place: local counting sort, ascending-address emission (verbatim r0) ----------------
__global__ __launch_bounds__(PTHREADS) void place_kernel(const int* __restrict__ src,
                                                         const int* __restrict__ dst,
                                                         int* __restrict__ gcursor,
                                                         unsigned int* __restrict__ packed) {
    __shared__ int h[512];
    __shared__ int ps[256];
    __shared__ int lstart[NB];
    __shared__ int gbase[NB];
    __shared__ int lcur[NB];
    __shared__ unsigned sortedv[EPB];
    __shared__ unsigned short binof[EPB];
    int t = threadIdx.x;
    h[t] = 0;
    __syncthreads();

    int base = blockIdx.x * EPB;
    int d[EPT], s[EPT];
    #pragma unroll
    for (int i = 0; i < EPT; ++i) {
        int e = base + t + i * PTHREADS;
        if (e < N_EDGES) {
            d[i] = dst[e]; s[i] = src[e];
            atomicAdd(&h[d[i] >> 8], 1);
        } else d[i] = -1;
    }
    __syncthreads();

    int a0 = 0, a1 = 0, pinc = 0;
    if (t < 256) {
        a0 = h[2 * t]; a1 = h[2 * t + 1];
        pinc = a0 + a1;
        ps[t] = pinc;
    }
    __syncthreads();
    for (int off = 1; off < 256; off <<= 1) {
        int y = (t < 256 && t >= off) ? ps[t - off] : 0;
        __syncthreads();
        if (t < 256) { pinc += y; ps[t] = pinc; }
        __syncthreads();
    }
    if (t < 256) {
        int pexc = pinc - a0 - a1;
        if (2 * t < NB) {
            lstart[2 * t] = pexc;
            lcur[2 * t] = pexc;
            gbase[2 * t] = a0 ? atomicAdd(&gcursor[2 * t], a0) : 0;
        }
        if (2 * t + 1 < NB) {
            lstart[2 * t + 1] = pexc + a0;
            lcur[2 * t + 1] = pexc + a0;
            gbase[2 * t + 1] = a1 ? atomicAdd(&gcursor[2 * t + 1], a1) : 0;
        }
    }
    __syncthreads();

    #pragma unroll
    for (int i = 0; i < EPT; ++i) {
        if (d[i] >= 0) {
            int b = d[i] >> 8;
            int pos = atomicAdd(&lcur[b], 1);
            sortedv[pos] = ((unsigned)s[i] << 8) | (unsigned)(d[i] & 255);
            binof[pos] = (unsigned short)b;
        }
    }
    __syncthreads();

    int cnt = min(EPB, N_EDGES - base);
    for (int k = t; k < cnt; k += PTHREADS) {
        int b = binof[k];
        int gp = gbase[b] + (k - lstart[b]);
        if (gp < (b + 1) * CAP) packed[gp] = sortedv[k];
    }
}

// ---------------- prep: per-bucket degree -> norm + fused bf16 featn (feat*norm) ----------------
__global__ __launch_bounds__(1024) void prep_kernel(const unsigned int* __restrict__ packed,
                                                    const int* __restrict__ gcursor,
                                                    float* __restrict__ norm,
                                                    const float* __restrict__ feat,
                                                    unsigned short* __restrict__ featn) {
    __shared__ int h[NPB];
    __shared__ float normf[NPB];
    int b = blockIdx.x, t = threadIdx.x;
    int beg = b * CAP;
    int end = min(gcursor[b], (b + 1) * CAP);
    if (t < NPB) h[t] = 0;
    __syncthreads();
    for (int j = beg + t; j < end; j += 1024)
        atomicAdd(&h[packed[j] & 255], 1);
    __syncthreads();
    int n0 = b * NPB;
    if (t < NPB) {
        int deg = h[t];
        float nv = rsqrtf((float)(deg < 1 ? 1 : deg));
        norm[n0 + t] = nv;
        normf[t] = nv;
    }
    __syncthreads();

    // fused prep for this bucket's 256 nodes (rows >= N_NODES zeroed)
    for (int idx = t; idx < NPB * 16; idx += 1024) {
        int nl = idx >> 4;
        int n = n0 + nl;
        uint2 r = make_uint2(0u, 0u);
        if (n < N_NODES) {
            float nn = normf[nl];
            float4 f = ((const float4*)feat)[(size_t)n * 16 + (idx & 15)];
            auto cvt = [](float x) -> unsigned {
                unsigned u = __float_as_uint(x);
                return (u + 0x7fff + ((u >> 16) & 1)) >> 16;
            };
            r.x = cvt(f.x * nn) | (cvt(f.y * nn) << 16);
            r.y = cvt(f.z * nn) | (cvt(f.w * nn) << 16);
        }
        ((uint2*)featn)[(size_t)n * 16 + (idx & 15)] = r;
    }
}

// ---------------- agg: per-bucket LDS f32 atomic aggregation ----------------
__global__ __launch_bounds__(1024) void agg_kernel(const unsigned int* __restrict__ packed,
                                                   const int* __restrict__ gcursor,
                                                   const unsigned short* __restrict__ featn,
                                                   float* __restrict__ aggG) {
    __shared__ float agg[NPB * AP];          // 256 nodes x 68-stride f32 = 69632 B
    int t = threadIdx.x;
    int b = blockIdx.x;
    int lane = t & 63;
    int w = t >> 6;                          // 16 waves

    #pragma unroll
    for (int i = t; i < NPB * AP; i += 1024) agg[i] = 0.f;
    __syncthreads();

    int beg = b * CAP;
    int end = min(gcursor[b], (b + 1) * CAP);
    int cnt = end - beg;
    int per = (cnt + 15) >> 4;               // contiguous chunk per wave
    int js = beg + w * per;
    int je = js + per; if (je > end) je = end;

    int j = js;
    for (; j + 4 <= je; j += 4) {
        unsigned p0 = packed[j],     p1 = packed[j + 1];
        unsigned p2 = packed[j + 2], p3 = packed[j + 3];
        unsigned short v0 = featn[(size_t)(p0 >> 8) * D + lane];
        unsigned short v1 = featn[(size_t)(p1 >> 8) * D + lane];
        unsigned short v2 = featn[(size_t)(p2 >> 8) * D + lane];
        unsigned short v3 = featn[(size_t)(p3 >> 8) * D + lane];
        atomicAdd(&agg[(p0 & 255) * AP + lane], __uint_as_float((unsigned)v0 << 16));
        atomicAdd(&agg[(p1 & 255) * AP + lane], __uint_as_float((unsigned)v1 << 16));
        atomicAdd(&agg[(p2 & 255) * AP + lane], __uint_as_float((unsigned)v2 << 16));
        atomicAdd(&agg[(p3 & 255) * AP + lane], __uint_as_float((unsigned)v3 << 16));
    }
    for (; j < je; ++j) {
        unsigned p = packed[j];
        unsigned short v = featn[(size_t)(p >> 8) * D + lane];
        atomicAdd(&agg[(p & 255) * AP + lane], __uint_as_float((unsigned)v << 16));
    }
    __syncthreads();

    // write out bucket agg rows (unnormed, f32), coalesced float4
    int n0 = b * NPB;
    for (int idx = t; idx < NPB * 16; idx += 1024) {
        int nl = idx >> 4, q = idx & 15;
        float4 v = *(const float4*)&agg[nl * AP + q * 4];
        ((float4*)aggG)[(size_t)(n0 + nl) * 16 + q] = v;
    }
}

// ---------------- gemm: stage agg*norm -> Hcol, 64x64 GEMM + bias ----------------
__global__ __launch_bounds__(256) void gemm_kernel(const float* __restrict__ aggG,
                                                   const float* __restrict__ norm,
                                                   const float* __restrict__ weight,
                                                   const float* __restrict__ bias,
                                                   float* __restrict__ out) {
    __shared__ float Hcol[D * HP];   // Hcol[k][n_local]
    __shared__ float Wt[D * HP];     // Wt[k][d]
    int tid = threadIdx.x;
    int base = blockIdx.x * 64;

    // stage W^T (k-major)
    #pragma unroll
    for (int i = tid; i < D * D; i += 256) {
        int c = i & 63, dd = i >> 6;
        Wt[c * HP + dd] = weight[dd * D + c];
    }
    // stage 64 agg rows, applying norm, transposed to k-major
    #pragma unroll
    for (int idx = tid; idx < 64 * 16; idx += 256) {
        int nl = idx >> 4, q = idx & 15;
        int n = base + nl;
        float4 v = ((const float4*)aggG)[(size_t)n * 16 + q];
        float nn = norm[n];
        Hcol[(q * 4 + 0) * HP + nl] = v.x * nn;
        Hcol[(q * 4 + 1) * HP + nl] = v.y * nn;
        Hcol[(q * 4 + 2) * HP + nl] = v.z * nn;
        Hcol[(q * 4 + 3) * HP + nl] = v.w * nn;
    }
    __syncthreads();

    int tx = tid & 15, ty = tid >> 4;
    float acc[4][4] = {};
    #pragma unroll 8
    for (int k = 0; k < D; ++k) {
        float4 a = *(const float4*)&Hcol[k * HP + ty * 4];
        float4 b = *(const float4*)&Wt[k * HP + tx * 4];
        acc[0][0] += a.x * b.x; acc[0][1] += a.x * b.y; acc[0][2] += a.x * b.z; acc[0][3] += a.x * b.w;
        acc[1][0] += a.y * b.x; acc[1][1] += a.y * b.y; acc[1][2] += a.y * b.z; acc[1][3] += a.y * b.w;
        acc[2][0] += a.z * b.x; acc[2][1] += a.z * b.y; acc[2][2] += a.z * b.z; acc[2][3] += a.z * b.w;
        acc[3][0] += a.w * b.x; acc[3][1] += a.w * b.y; acc[3][2] += a.w * b.z; acc[3][3] += a.w * b.w;
    }
    float4 bv = *(const float4*)&bias[tx * 4];
    #pragma unroll
    for (int i = 0; i < 4; ++i) {
        int n = base + ty * 4 + i;
        if (n < N_NODES) {
            *(float4*)&out[(size_t)n * D + tx * 4] =
                make_float4(acc[i][0] + bv.x, acc[i][1] + bv.y,
                            acc[i][2] + bv.z, acc[i][3] + bv.w);
        }
    }
}

extern "C" void kernel_launch(void* const* d_in, const int* in_sizes, int n_in,
                              void* d_out, int out_size, void* d_ws, size_t ws_size,
                              hipStream_t stream) {
    const float* feat   = (const float*)d_in[0];
    const int*   src    = (const int*)d_in[1];
    const int*   dst    = (const int*)d_in[2];
    const float* weight = (const float*)d_in[3];
    const float* bias   = (const float*)d_in[4];
    float* out = (float*)d_out;

    // workspace layout (4-byte units); high water ~45 MB
    int* w = (int*)d_ws;
    int*      gcursor = w;                                    // [NB]
    float*    norm    = (float*)(gcursor + NB);               // [NPAD2]
    unsigned* packed  = (unsigned*)(norm + NPAD2);            // [NB*CAP]
    size_t featn_off = (size_t)NB + (size_t)NPAD2 + (size_t)NB * CAP;
    featn_off = (featn_off + 3) & ~(size_t)3;                 // 16B-align
    unsigned short* featn = (unsigned short*)(w + featn_off); // [NPAD2*D] bf16
    size_t agg_off = featn_off + ((size_t)NPAD2 * D) / 2;     // ushort = half an int
    agg_off = (agg_off + 3) & ~(size_t)3;                     // 16B-align
    float* aggG = (float*)(w + agg_off);                      // [NPAD2*D] f32

    init_kernel <<<2, 256, 0, stream>>>(gcursor);
    place_kernel<<<NBLK, PTHREADS, 0, stream>>>(src, dst, gcursor, packed);
    prep_kernel <<<NB, 1024, 0, stream>>>(packed, gcursor, norm, feat, featn);
    agg_kernel  <<<NB, 1024, 0, stream>>>(packed, gcursor, featn, aggG);
    gemm_kernel <<<(N_NODES + 63) / 64, 256, 0, stream>>>(aggG, norm, weight, bias, out);
}

// Round 3
// 174.596 us; speedup vs baseline: 3.8050x; 3.8050x over previous
//
#include <hip/hip_runtime.h>

#define N_NODES 100000
#define N_EDGES 1250000
#define D 64
#define NPB 256                  // nodes per coarse bucket (dst >> 8)
#define NB  391                  // ceil(N_NODES / NPB)
#define NPAD2 (NB * NPB)         // 100096
#define PTHREADS 512
#define EPT 8                    // edges per thread in place
#define EPB (PTHREADS * EPT)     // 4096 edges per block
#define NBLK ((N_EDGES + EPB - 1) / EPB)   // 306
#define CAP  4096                // static per-bucket capacity (mean 3197, +15 sigma)
#define CAPPAD 1792              // extra capacity for pad-to-8 (256*7)
#define CAPP (CAP + CAPPAD)      // 5888: per-bucket stride in ssp
#define DUMMY N_NODES            // featW[DUMMY] is a zero row
#define HP 68                    // LDS leading-dim pad (16B-aligned float4 rows)

// ---------------- init: gcursor[b] = b*CAP ----------------
__global__ void init_kernel(int* __restrict__ gcursor) {
    int i = blockIdx.x * 256 + threadIdx.x;
    if (i < NB) gcursor[i] = i * CAP;
}

// ---------------- place: local counting sort, ascending-address emission (verbatim r0) ----------------
__global__ __launch_bounds__(PTHREADS) void place_kernel(const int* __restrict__ src,
                                                         const int* __restrict__ dst,
                                                         int* __restrict__ gcursor,
                                                         unsigned int* __restrict__ packed) {
    __shared__ int h[512];
    __shared__ int ps[256];
    __shared__ int lstart[NB];
    __shared__ int gbase[NB];
    __shared__ int lcur[NB];
    __shared__ unsigned sortedv[EPB];
    __shared__ unsigned short binof[EPB];
    int t = threadIdx.x;
    h[t] = 0;
    __syncthreads();

    int base = blockIdx.x * EPB;
    int d[EPT], s[EPT];
    #pragma unroll
    for (int i = 0; i < EPT; ++i) {
        int e = base + t + i * PTHREADS;
        if (e < N_EDGES) {
            d[i] = dst[e]; s[i] = src[e];
            atomicAdd(&h[d[i] >> 8], 1);
        } else d[i] = -1;
    }
    __syncthreads();

    int a0 = 0, a1 = 0, pinc = 0;
    if (t < 256) {
        a0 = h[2 * t]; a1 = h[2 * t + 1];
        pinc = a0 + a1;
        ps[t] = pinc;
    }
    __syncthreads();
    for (int off = 1; off < 256; off <<= 1) {
        int y = (t < 256 && t >= off) ? ps[t - off] : 0;
        __syncthreads();
        if (t < 256) { pinc += y; ps[t] = pinc; }
        __syncthreads();
    }
    if (t < 256) {
        int pexc = pinc - a0 - a1;
        if (2 * t < NB) {
            lstart[2 * t] = pexc;
            lcur[2 * t] = pexc;
            gbase[2 * t] = a0 ? atomicAdd(&gcursor[2 * t], a0) : 0;
        }
        if (2 * t + 1 < NB) {
            lstart[2 * t + 1] = pexc + a0;
            lcur[2 * t + 1] = pexc + a0;
            gbase[2 * t + 1] = a1 ? atomicAdd(&gcursor[2 * t + 1], a1) : 0;
        }
    }
    __syncthreads();

    #pragma unroll
    for (int i = 0; i < EPT; ++i) {
        if (d[i] >= 0) {
            int b = d[i] >> 8;
            int pos = atomicAdd(&lcur[b], 1);
            sortedv[pos] = ((unsigned)s[i] << 8) | (unsigned)(d[i] & 255);
            binof[pos] = (unsigned short)b;
        }
    }
    __syncthreads();

    int cnt = min(EPB, N_EDGES - base);
    for (int k = t; k < cnt; k += PTHREADS) {
        int b = binof[k];
        int gp = gbase[b] + (k - lstart[b]);
        if (gp < (b + 1) * CAP) packed[gp] = sortedv[k];
    }
}

// ---------------- refine: padded CSR + norm (r0 minus featn tail) ----------------
__global__ __launch_bounds__(1024) void refine_kernel(const unsigned int* __restrict__ packed,
                                                      const int* __restrict__ gcursor,
                                                      int* __restrict__ ssp,
                                                      int* __restrict__ pbeg,
                                                      int* __restrict__ pdega,
                                                      float* __restrict__ norm) {
    __shared__ int h[NPB];
    __shared__ int sc[NPB];
    __shared__ int cur[NPB];
    int b = blockIdx.x, t = threadIdx.x;
    int beg = b * CAP;
    int end = min(gcursor[b], (b + 1) * CAP);
    if (t < NPB) h[t] = 0;
    __syncthreads();
    for (int j = beg + t; j < end; j += 1024)
        atomicAdd(&h[packed[j] & 255], 1);
    __syncthreads();
    int deg = 0, pdeg = 0, inc = 0;
    if (t < NPB) {
        deg = h[t];
        pdeg = (deg + 7) & ~7;
        inc = pdeg;
        sc[t] = inc;
    }
    __syncthreads();
    for (int off = 1; off < 256; off <<= 1) {
        int y = (t < NPB && t >= off) ? sc[t - off] : 0;
        __syncthreads();
        if (t < NPB) { inc += y; sc[t] = inc; }
        __syncthreads();
    }
    int pb = 0;
    if (t < NPB) {
        int exc = inc - pdeg;
        pb = b * CAPP + exc;
        cur[t] = pb;
        int n = b * NPB + t;
        pbeg[n] = pb;
        pdega[n] = pdeg;
        norm[n] = rsqrtf((float)(deg < 1 ? 1 : deg));
    }
    __syncthreads();
    for (int j = beg + t; j < end; j += 1024) {
        unsigned p = packed[j];
        int pos = atomicAdd(&cur[p & 255], 1);
        ssp[pos] = (int)(p >> 8);
    }
    __syncthreads();
    if (t < NPB) {
        int fend = pb + pdeg;
        for (int k = cur[t]; k < fend; ++k) ssp[k] = DUMMY;
    }
}

// ---------------- featw: featW[n] = bf16(norm[n] * (feat[n] @ W^T)), zeros past N_NODES ----------------
__global__ __launch_bounds__(256) void featw_kernel(const float* __restrict__ feat,
                                                    const float* __restrict__ norm,
                                                    const float* __restrict__ weight,
                                                    unsigned short* __restrict__ featW) {
    __shared__ float Hcol[D * HP];   // Hcol[k][n_local] = feat[n][k]*norm[n]
    __shared__ float Wt[D * HP];     // Wt[k][d]
    int tid = threadIdx.x;
    int base = blockIdx.x * 64;

    #pragma unroll
    for (int i = tid; i < D * D; i += 256) {
        int c = i & 63, dd = i >> 6;
        Wt[c * HP + dd] = weight[dd * D + c];
    }
    #pragma unroll
    for (int idx = tid; idx < 64 * 16; idx += 256) {
        int nl = idx >> 4, q = idx & 15;
        int n = base + nl;
        float4 v = make_float4(0.f, 0.f, 0.f, 0.f);
        float nn = 0.f;
        if (n < N_NODES) {
            v = ((const float4*)feat)[(size_t)n * 16 + q];
            nn = norm[n];
        }
        Hcol[(q * 4 + 0) * HP + nl] = v.x * nn;
        Hcol[(q * 4 + 1) * HP + nl] = v.y * nn;
        Hcol[(q * 4 + 2) * HP + nl] = v.z * nn;
        Hcol[(q * 4 + 3) * HP + nl] = v.w * nn;
    }
    __syncthreads();

    int tx = tid & 15, ty = tid >> 4;
    float acc[4][4] = {};
    #pragma unroll 8
    for (int k = 0; k < D; ++k) {
        float4 a = *(const float4*)&Hcol[k * HP + ty * 4];
        float4 b = *(const float4*)&Wt[k * HP + tx * 4];
        acc[0][0] += a.x * b.x; acc[0][1] += a.x * b.y; acc[0][2] += a.x * b.z; acc[0][3] += a.x * b.w;
        acc[1][0] += a.y * b.x; acc[1][1] += a.y * b.y; acc[1][2] += a.y * b.z; acc[1][3] += a.y * b.w;
        acc[2][0] += a.z * b.x; acc[2][1] += a.z * b.y; acc[2][2] += a.z * b.z; acc[2][3] += a.z * b.w;
        acc[3][0] += a.w * b.x; acc[3][1] += a.w * b.y; acc[3][2] += a.w * b.z; acc[3][3] += a.w * b.w;
    }
    auto cvt = [](float x) -> unsigned {
        unsigned u = __float_as_uint(x);
        return (u + 0x7fff + ((u >> 16) & 1)) >> 16;
    };
    #pragma unroll
    for (int i = 0; i < 4; ++i) {
        int n = base + ty * 4 + i;    // always < NPAD2; rows >= N_NODES get exact zeros
        uint2 r;
        r.x = cvt(acc[i][0]) | (cvt(acc[i][1]) << 16);
        r.y = cvt(acc[i][2]) | (cvt(acc[i][3]) << 16);
        *(uint2*)&featW[(size_t)n * D + tx * 4] = r;
    }
}

// ---------------- gather_out: pure CSR gather -> *norm[dst] + bias -> out ----------------
#define ACC_EDGE(ACC, J) do {                                         \
        int s_ = ssp[(J)];                                            \
        uint2 r_ = *(const uint2*)&featW[(size_t)s_ * D + m * 4];     \
        ACC.x += __uint_as_float(r_.x << 16);                         \
        ACC.y += __uint_as_float(r_.x & 0xffff0000u);                 \
        ACC.z += __uint_as_float(r_.y << 16);                         \
        ACC.w += __uint_as_float(r_.y & 0xffff0000u);                 \
    } while (0)
#define ACC4(ACC, J) { ACC_EDGE(ACC, (J) + q); ACC_EDGE(ACC, (J) + 4 + q); \
                       ACC_EDGE(ACC, (J) + 8 + q); ACC_EDGE(ACC, (J) + 12 + q); }
#define ACC2(ACC, J) { ACC_EDGE(ACC, (J) + q); ACC_EDGE(ACC, (J) + 4 + q); }

__global__ __launch_bounds__(512) void gather_out_kernel(const unsigned short* __restrict__ featW,
                                                         const int* __restrict__ ssp,
                                                         const int* __restrict__ pbeg,
                                                         const int* __restrict__ pdega,
                                                         const float* __restrict__ norm,
                                                         const float* __restrict__ bias,
                                                         float* __restrict__ out) {
    int tid = threadIdx.x;
    int base = blockIdx.x * 32;          // 8 waves x 4 nodes
    int w = tid >> 6;
    int lane = tid & 63;
    int q = lane >> 4, m = lane & 15;
    float4 bv = ((const float4*)bias)[m];

    #pragma unroll
    for (int pr = 0; pr < 2; ++pr) {
        int nA = base + w * 4 + pr * 2;
        int nB = nA + 1;
        int begA = pbeg[nA], endA = begA + pdega[nA];
        int begB = pbeg[nB], endB = begB + pdega[nB];
        float4 aA = make_float4(0.f, 0.f, 0.f, 0.f);
        float4 aB = make_float4(0.f, 0.f, 0.f, 0.f);
        int jA = begA, jB = begB;
        while (jA + 16 <= endA && jB + 16 <= endB) {   // 8 row-loads in flight
            ACC4(aA, jA); ACC4(aB, jB);
            jA += 16; jB += 16;
        }
        for (; jA + 16 <= endA; jA += 16) ACC4(aA, jA);
        for (; jB + 16 <= endB; jB += 16) ACC4(aB, jB);
        if (jA < endA) ACC2(aA, jA);                    // exactly 8 remain
        if (jB < endB) ACC2(aB, jB);

        #pragma unroll
        for (int mask = 16; mask <= 32; mask <<= 1) {
            aA.x += __shfl_xor(aA.x, mask); aA.y += __shfl_xor(aA.y, mask);
            aA.z += __shfl_xor(aA.z, mask); aA.w += __shfl_xor(aA.w, mask);
            aB.x += __shfl_xor(aB.x, mask); aB.y += __shfl_xor(aB.y, mask);
            aB.z += __shfl_xor(aB.z, mask); aB.w += __shfl_xor(aB.w, mask);
        }
        float nnA = norm[nA], nnB = norm[nB];
        if (q == 0 && nA < N_NODES) {
            *(float4*)&out[(size_t)nA * D + m * 4] =
                make_float4(aA.x * nnA + bv.x, aA.y * nnA + bv.y,
                            aA.z * nnA + bv.z, aA.w * nnA + bv.w);
        }
        if (q == 1 && nB < N_NODES) {
            *(float4*)&out[(size_t)nB * D + m * 4] =
                make_float4(aB.x * nnB + bv.x, aB.y * nnB + bv.y,
                            aB.z * nnB + bv.z, aB.w * nnB + bv.w);
        }
    }
}

extern "C" void kernel_launch(void* const* d_in, const int* in_sizes, int n_in,
                              void* d_out, int out_size, void* d_ws, size_t ws_size,
                              hipStream_t stream) {
    const float* feat   = (const float*)d_in[0];
    const int*   src    = (const int*)d_in[1];
    const int*   dst    = (const int*)d_in[2];
    const float* weight = (const float*)d_in[3];
    const float* bias   = (const float*)d_in[4];
    float* out = (float*)d_out;

    // workspace layout (4-byte units); high water ~30 MB
    int* w = (int*)d_ws;
    int*      gcursor = w;                                   // [NB]
    int*      pbeg    = gcursor + NB;                        // [NPAD2]
    int*      pdega   = pbeg + NPAD2;                        // [NPAD2]
    float*    norm    = (float*)(pdega + NPAD2);             // [NPAD2]
    int*      ssp     = (int*)(norm + NPAD2);                // [NB*CAPP]
    unsigned* packed  = (unsigned*)(ssp + (size_t)NB * CAPP);// [NB*CAP]
    size_t featW_off = (size_t)NB + 3 * (size_t)NPAD2 + (size_t)NB * CAPP + (size_t)NB * CAP;
    featW_off = (featW_off + 3) & ~(size_t)3;                // 16B-align
    unsigned short* featW = (unsigned short*)(w + featW_off);// [NPAD2*D] bf16

    init_kernel      <<<2, 256, 0, stream>>>(gcursor);
    place_kernel     <<<NBLK, PTHREADS, 0, stream>>>(src, dst, gcursor, packed);
    refine_kernel    <<<NB, 1024, 0, stream>>>(packed, gcursor, ssp, pbeg, pdega, norm);
    featw_kernel     <<<(NPAD2 + 63) / 64, 256, 0, stream>>>(feat, norm, weight, featW);
    gather_out_kernel<<<(NPAD2 + 31) / 32, 512, 0, stream>>>(featW, ssp, pbeg, pdega, norm,
                                                             bias, out);
}